// Round 13
// baseline (239.733 us; speedup 1.0000x reference)
//
#include <hip/hip_runtime.h>
#include <hip/hip_cooperative_groups.h>

namespace cg = cooperative_groups;

// LaterallyConnectedLayer: B=16, NUM_FM=64, N=4, NF=256, H=W=32, KS=5. fp32 I/O.
//   w1[i][o][k]   = minmax5x5( K[i][o] )
//   wsum[o][g][k] = sum_n w1[64n+g][o][k]
//   score[b,o]    = (sum-1024*min)/(max-min) over conv_same(A[b,:],wsum[o,:])*S[o]
//   n*[b,f]       = argmax_n score[b,64n+f]
//   out[b,f]      = (1/64) sum_g conv_same(A[b,g], w1[ig_g][ig_f]), ig_x = 64n*_x + x
// Implicit GEMMs on mfma_f32_16x16x32_bf16, fp32 hi/lo split (hh+hl+lh).
// k_global = dydx*64 + g -> chunk ks = dydx*2+(g>=32); in-chunk k = quad*8+j.
// R13: single COOPERATIVE kernel, 4 phases separated by grid.sync() — removes
// 3 launch boundaries (~25us of the 142us total was inter-launch gap; kernels
// sum to ~73 + 43.6 harness poison-fill). Phase bodies = frozen R6 code
// (141.4/142.0us, best): kw bid<64, kscore all 256 blocks, kpackO bid<128,
// kout restructured to 256 blocks x 8 waves (4 ftile x 2 xh) sharing one
// 36-wide slab -> per-CU weight L2 stream halves (800->400KB), A staged once.
// kscore's 3.94M SQ_LDS_BANK_CONFLICT is benign 2-way aliasing (R10 proof).

#define NFM 64
#define NMX 4
#define NFC 256
#define HW 1024
#define KK 25

typedef unsigned short u16;
typedef short short8 __attribute__((ext_vector_type(8)));
typedef float f32x4 __attribute__((ext_vector_type(4)));

__device__ __forceinline__ u16 f2bfbits(float f) {
    unsigned int u = __float_as_uint(f);
    u += 0x7fffu + ((u >> 16) & 1u);   // RNE
    return (u16)(u >> 16);
}
__device__ __forceinline__ float bf2f(u16 v) {
    return __uint_as_float(((unsigned int)v) << 16);
}

#define MFMA6(P, BH, BL)                                                             \
    acc[0][P] = __builtin_amdgcn_mfma_f32_16x16x32_bf16(cah0, BH, acc[0][P], 0, 0, 0); \
    acc[1][P] = __builtin_amdgcn_mfma_f32_16x16x32_bf16(cah1, BH, acc[1][P], 0, 0, 0); \
    acc[0][P] = __builtin_amdgcn_mfma_f32_16x16x32_bf16(cah0, BL, acc[0][P], 0, 0, 0); \
    acc[1][P] = __builtin_amdgcn_mfma_f32_16x16x32_bf16(cah1, BL, acc[1][P], 0, 0, 0); \
    acc[0][P] = __builtin_amdgcn_mfma_f32_16x16x32_bf16(cal0, BH, acc[0][P], 0, 0, 0); \
    acc[1][P] = __builtin_amdgcn_mfma_f32_16x16x32_bf16(cal1, BH, acc[1][P], 0, 0, 0);

__global__ __launch_bounds__(512, 1) void kfused(const float* __restrict__ A,
                                                 const float* __restrict__ K,
                                                 const float* __restrict__ S,
                                                 char* __restrict__ Wpk,
                                                 char* __restrict__ Wob,
                                                 float4* __restrict__ part,
                                                 float* __restrict__ out) {
    __shared__ __align__(16) char smem[62464];
    cg::grid_group grid = cg::this_grid();
    int t = threadIdx.x;
    int bid = blockIdx.y * 16 + blockIdx.x;
    int lane = t & 63;
    int wv = __builtin_amdgcn_readfirstlane(t >> 6);   // 0..7
    int n15 = lane & 15, quad = lane >> 4;

    // ===== Phase 1: kw (fused kprep+kpackW), bid<64, work on t<256 ==========
    if (bid < 64) {
        float* wlds = (float*)smem;                    // 16*16*25 f = 25600 B
        int gq = bid & 3, ot = bid >> 2;
        if (t < 256) {
            int tg = t >> 4, to = t & 15;
            int g = gq * 16 + tg, o = ot * 16 + to;
            float wacc[KK];
#pragma unroll
            for (int k = 0; k < KK; ++k) wacc[k] = 0.f;
#pragma unroll
            for (int n = 0; n < NMX; ++n) {
                const float* src = K + ((n * NFM + g) * NFC + o) * KK;
                float v[KK];
                float mn = 1e30f, mx = -1e30f;
#pragma unroll
                for (int k = 0; k < KK; ++k) {
                    v[k] = src[k];
                    mn = fminf(mn, v[k]);
                    mx = fmaxf(mx, v[k]);
                }
                float d = mx - mn;
                float r = d > 0.f ? 1.f / d : 0.f;
#pragma unroll
                for (int k = 0; k < KK; ++k) wacc[k] += (v[k] - mn) * r;
            }
#pragma unroll
            for (int k = 0; k < KK; ++k) wlds[(tg * 16 + to) * KK + k] = wacc[k];
        }
        __syncthreads();
        int gh = gq >> 1;
        for (int idx = t; idx < KK * 32; idx += 512) {
            int dydx = idx >> 5, l32 = idx & 31;
            int qd = (gq & 1) * 2 + (l32 >> 4);
            int oo = l32 & 15;
            int l = qd * 16 + oo;
            short8 hs, ls;
#pragma unroll
            for (int j = 0; j < 8; ++j) {
                int gl = (l32 >> 4) * 8 + j;
                float v = wlds[(gl * 16 + oo) * KK + dydx];
                u16 h = f2bfbits(v);
                hs[j] = (short)h;
                ls[j] = (short)f2bfbits(v - bf2f(h));
            }
            char* cb = Wpk + (ot * 50 + dydx * 2 + gh) * 2048 + l * 16;
            *(short8*)cb = hs;
            *(short8*)(cb + 1024) = ls;
        }
    }
    grid.sync();

    // ===== Phase 2: kscore (R6-exact body), all 256 blocks ==================
    {
        u16* slabh = (u16*)smem;                       // 6*36*72 u16 = 15552
        u16* slabl = slabh + 6 * 36 * 72;              // total 62208 B
        int y2 = blockIdx.x, b = blockIdx.y;
        int y0 = y2 * 2;

        const float* Ab = A + b * NFM * HW;
        for (int ry = 0; ry < 6; ++ry) {
            int gy = y0 - 2 + ry;
            bool rowok = (gy >= 0) && (gy < 32);
            for (int c = 0; c < 5; ++c) {
                int id2 = c * 512 + t;               // g*36 + xi, < 2304
                if (id2 < 2304) {
                    int g = (id2 * 3641) >> 17;      // exact /36 for id2<2304
                    int xi = id2 - g * 36;
                    float v = 0.f;
                    if (rowok && xi >= 2 && xi < 34)
                        v = Ab[g * HW + gy * 32 + xi - 2];
                    u16 h = f2bfbits(v);
                    u16 l = f2bfbits(v - bf2f(h));
                    int idx = (ry * 36 + xi) * 72 + g;
                    slabh[idx] = h;
                    slabl[idx] = l;
                }
            }
        }
        __syncthreads();

        f32x4 acc[2][4];
#pragma unroll
        for (int m = 0; m < 2; ++m)
#pragma unroll
            for (int p = 0; p < 4; ++p)
#pragma unroll
                for (int r = 0; r < 4; ++r) acc[m][p][r] = 0.f;

        const char* wbase0 = Wpk + (wv * 2) * 50 * 2048 + lane * 16;
        const char* wbase1 = wbase0 + 50 * 2048;
        short8 cah0 = *(const short8*)(wbase0);
        short8 cal0 = *(const short8*)(wbase0 + 1024);
        short8 cah1 = *(const short8*)(wbase1);
        short8 cal1 = *(const short8*)(wbase1 + 1024);

        int rb0 = n15 * 72 + quad * 8;
        const u16* sh0 = slabh + rb0;
        const u16* sl0 = slabl + rb0;
        short8 bh0 = *(const short8*)(sh0);
        short8 bl0 = *(const short8*)(sl0);
        short8 bh1 = *(const short8*)(sh0 + 16 * 72);
        short8 bl1 = *(const short8*)(sl0 + 16 * 72);
        short8 bh2 = *(const short8*)(sh0 + 36 * 72);
        short8 bl2 = *(const short8*)(sl0 + 36 * 72);
        short8 bh3 = *(const short8*)(sh0 + 52 * 72);
        short8 bl3 = *(const short8*)(sl0 + 52 * 72);

        for (int ks = 0; ks < 50; ++ks) {
            int ksn = ks < 49 ? ks + 1 : 49;
            const char* nb0 = wbase0 + (ksn << 11);
            const char* nb1 = wbase1 + (ksn << 11);
            short8 nah0 = *(const short8*)nb0;
            short8 nal0 = *(const short8*)(nb0 + 1024);
            short8 nah1 = *(const short8*)nb1;
            short8 nal1 = *(const short8*)(nb1 + 1024);
            int dydxn = ksn >> 1;
            int ghn = (ksn & 1) * 32;
            int dyn = dydxn / 5, dxn = dydxn - dyn * 5;
            int rbn = (dyn * 36 + n15 + dxn) * 72 + ghn + quad * 8;
            const u16* shn = slabh + rbn;
            const u16* sln = slabl + rbn;
            short8 nh0 = *(const short8*)(shn);
            short8 nl0 = *(const short8*)(sln);
            short8 nh1 = *(const short8*)(shn + 16 * 72);
            short8 nl1 = *(const short8*)(sln + 16 * 72);
            short8 nh2 = *(const short8*)(shn + 36 * 72);
            short8 nl2 = *(const short8*)(sln + 36 * 72);
            short8 nh3 = *(const short8*)(shn + 52 * 72);
            short8 nl3 = *(const short8*)(sln + 52 * 72);
            __builtin_amdgcn_sched_barrier(0);

            MFMA6(0, bh0, bl0)
            MFMA6(1, bh1, bl1)
            MFMA6(2, bh2, bl2)
            MFMA6(3, bh3, bl3)

            bh0 = nh0; bl0 = nl0; bh1 = nh1; bl1 = nl1;
            bh2 = nh2; bl2 = nl2; bh3 = nh3; bl3 = nl3;
            cah0 = nah0; cal0 = nal0; cah1 = nah1; cal1 = nal1;
        }

#pragma unroll
        for (int m = 0; m < 2; ++m) {
#pragma unroll
            for (int reg = 0; reg < 4; ++reg) {
                float v0 = acc[m][0][reg], v1 = acc[m][1][reg];
                float v2 = acc[m][2][reg], v3 = acc[m][3][reg];
                float mn = fminf(fminf(v0, v1), fminf(v2, v3));
                float mx = fmaxf(fmaxf(v0, v1), fmaxf(v2, v3));
                float sm = (v0 + v1) + (v2 + v3);
#pragma unroll
                for (int msk = 1; msk <= 8; msk <<= 1) {
                    mn = fminf(mn, __shfl_xor(mn, msk, 64));
                    mx = fmaxf(mx, __shfl_xor(mx, msk, 64));
                    sm += __shfl_xor(sm, msk, 64);
                }
                if (n15 == 0) {
                    int o = (wv * 2 + m) * 16 + quad * 4 + reg;
                    part[(b * NFC + o) * 16 + y2] = make_float4(mn, mx, sm, 0.f);
                }
            }
        }
    }
    grid.sync();

    // ===== Phase 3: kpackO, bid<128, work on t<256 ==========================
    if (bid < 128) {
        float* scl = (float*)smem;                     // 1024 B
        int* igL = (int*)(smem + 1024);                // 256 B
        char* cbuf = smem + 2048;                      // 51200 B
        int ft = bid & 3, b = (bid >> 2) & 15, half = bid >> 6;
        if (t < 256) {
            const float4* pp = part + (b * NFC + t) * 16;
            float mn = 1e30f, mx = -1e30f, sm = 0.f;
#pragma unroll
            for (int r = 0; r < 16; ++r) {
                float4 p = pp[r];
                mn = fminf(mn, p.x);
                mx = fmaxf(mx, p.y);
                sm += p.z;
            }
            float s = S[t] * (1.f / 64.f);
            float mnv = (s >= 0.f ? mn : mx) * s;
            float mxv = (s >= 0.f ? mx : mn) * s;
            float smv = sm * s;
            float d = mxv - mnv;
            scl[t] = d > 0.f ? (smv - 1024.f * mnv) / d : 0.f;
        }
        __syncthreads();
        if (t < NFM) {
            float best = scl[t];
            int bi = 0;
#pragma unroll
            for (int n = 1; n < NMX; ++n) {
                float v = scl[n * NFM + t];
                if (v > best) { best = v; bi = n; }   // first-max ties
            }
            igL[t] = bi * NFM + t;
        }
        __syncthreads();

        char* wdst = Wob + b * 409600 + ft * 102400;
        if (t < 256) {
            int g32 = t & 31, fh = t >> 5;
            int qd = g32 >> 3, j = g32 & 7;
            int i = igL[half * 32 + g32];
#pragma unroll
            for (int e = 0; e < 2; ++e) {
                int f15 = fh * 2 + e;
                int o = igL[ft * 16 + f15];
                const float* src = K + (i * NFC + o) * KK;
                float v[KK];
                float mn = 1e30f, mx = -1e30f;
#pragma unroll
                for (int k = 0; k < KK; ++k) {
                    v[k] = src[k];
                    mn = fminf(mn, v[k]);
                    mx = fmaxf(mx, v[k]);
                }
                float d = mx - mn;
                float r = d > 0.f ? 1.f / d : 0.f;
                char* base = cbuf + (qd * 16 + f15) * 16 + j * 2;
#pragma unroll
                for (int k = 0; k < KK; ++k) {
                    float nv = (v[k] - mn) * r;
                    u16 h = f2bfbits(nv);
                    u16 l = f2bfbits(nv - bf2f(h));
                    *(u16*)(base + k * 2048) = h;
                    *(u16*)(base + k * 2048 + 1024) = l;
                }
            }
        }
        __syncthreads();
        for (int idx = t; idx < 3200; idx += 512) {   // 25 chunks x 128 f4
            int ch = idx >> 7, w = idx & 127;
            *(float4*)(wdst + (ch * 2 + half) * 2048 + w * 16) =
                *(const float4*)(cbuf + ch * 2048 + w * 16);
        }
    }
    grid.sync();

    // ===== Phase 4: kout, all 256 blocks, 8 waves = 4 ftile x 2 xh ==========
    {
        u16* slabh = (u16*)smem;                       // shared 36-wide slab
        u16* slabl = slabh + 6 * 36 * 72;
        int yb2 = blockIdx.x, b = blockIdx.y;
        int y0 = yb2 * 2;
        int ftile = wv & 3, xh = wv >> 2;
        int xoff = xh * 16;

        const float* Ab = A + b * NFM * HW;
        for (int ry = 0; ry < 6; ++ry) {
            int gy = y0 - 2 + ry;
            bool rowok = (gy >= 0) && (gy < 32);
            for (int c = 0; c < 5; ++c) {
                int id2 = c * 512 + t;
                if (id2 < 2304) {
                    int g = (id2 * 3641) >> 17;
                    int xi = id2 - g * 36;
                    float v = 0.f;
                    if (rowok && xi >= 2 && xi < 34)
                        v = Ab[g * HW + gy * 32 + xi - 2];
                    u16 h = f2bfbits(v);
                    u16 l = f2bfbits(v - bf2f(h));
                    int idx = (ry * 36 + xi) * 72 + g;
                    slabh[idx] = h;
                    slabl[idx] = l;
                }
            }
        }
        __syncthreads();

        f32x4 acc2[2];
#pragma unroll
        for (int r = 0; r < 2; ++r)
#pragma unroll
            for (int jr = 0; jr < 4; ++jr) acc2[r][jr] = 0.f;

        const char* wbase = Wob + b * 409600 + (ftile * 50) * 2048 + lane * 16;
        short8 cah = *(const short8*)(wbase);
        short8 cal = *(const short8*)(wbase + 1024);

        int rb0 = (xoff + n15) * 72 + quad * 8;
        short8 bh0 = *(const short8*)(slabh + rb0);
        short8 bl0 = *(const short8*)(slabl + rb0);
        short8 bh1 = *(const short8*)(slabh + rb0 + 36 * 72);
        short8 bl1 = *(const short8*)(slabl + rb0 + 36 * 72);

        for (int ks = 0; ks < 50; ++ks) {
            int ksn = ks < 49 ? ks + 1 : 49;
            const char* nb = wbase + (ksn << 11);
            short8 nah = *(const short8*)nb;
            short8 nal = *(const short8*)(nb + 1024);

            int dydxn = ksn >> 1;
            int ghn = (ksn & 1) * 32;
            int dyn = dydxn / 5, dxn = dydxn - dyn * 5;
            int rbn = (dyn * 36 + xoff + n15 + dxn) * 72 + ghn + quad * 8;
            short8 nh0 = *(const short8*)(slabh + rbn);
            short8 nl0 = *(const short8*)(slabl + rbn);
            short8 nh1 = *(const short8*)(slabh + rbn + 36 * 72);
            short8 nl1 = *(const short8*)(slabl + rbn + 36 * 72);
            __builtin_amdgcn_sched_barrier(0);

            acc2[0] = __builtin_amdgcn_mfma_f32_16x16x32_bf16(cah, bh0, acc2[0], 0, 0, 0);
            acc2[1] = __builtin_amdgcn_mfma_f32_16x16x32_bf16(cah, bh1, acc2[1], 0, 0, 0);
            acc2[0] = __builtin_amdgcn_mfma_f32_16x16x32_bf16(cah, bl0, acc2[0], 0, 0, 0);
            acc2[1] = __builtin_amdgcn_mfma_f32_16x16x32_bf16(cah, bl1, acc2[1], 0, 0, 0);
            acc2[0] = __builtin_amdgcn_mfma_f32_16x16x32_bf16(cal, bh0, acc2[0], 0, 0, 0);
            acc2[1] = __builtin_amdgcn_mfma_f32_16x16x32_bf16(cal, bh1, acc2[1], 0, 0, 0);

            bh0 = nh0; bl0 = nl0; bh1 = nh1; bl1 = nl1;
            cah = nah;
            cal = nal;
        }

#pragma unroll
        for (int r = 0; r < 2; ++r)
#pragma unroll
            for (int reg = 0; reg < 4; ++reg) {
                int f = ftile * 16 + quad * 4 + reg;
                out[(b * NFM + f) * HW + (y0 + r) * 32 + xoff + n15] =
                    acc2[r][reg] * (1.f / 64.f);
            }
    }
}

extern "C" void kernel_launch(void* const* d_in, const int* in_sizes, int n_in,
                              void* d_out, int out_size, void* d_ws, size_t ws_size,
                              hipStream_t stream) {
    const float* A = (const float*)d_in[0];   // (16,64,32,32) f32
    const float* K = (const float*)d_in[1];   // (256,256,5,5) f32
    const float* S = (const float*)d_in[2];   // (256,) f32
    float* out = (float*)d_out;               // (16,64,32,32) f32

    char* ws = (char*)d_ws;
    char*   Wob   = ws;                         // [0, 6,553,600) phase-3 output
    char*   Wpk   = ws;                         // [0, 1,638,400) dead before phase 3
    float4* part  = (float4*)(ws + 6553600);    // [6.55M, 7.60M) 16*256*16 f4

    void* args[] = {(void*)&A, (void*)&K, (void*)&S, (void*)&Wpk,
                    (void*)&Wob, (void*)&part, (void*)&out};
    hipLaunchCooperativeKernel((void*)kfused, dim3(16, 16), dim3(512), args, 0, stream);
}

// Round 14
// 141.082 us; speedup vs baseline: 1.6993x; 1.6993x over previous
//
#include <hip/hip_runtime.h>

// LaterallyConnectedLayer: B=16, NUM_FM=64, N=4, NF=256, H=W=32, KS=5. fp32 I/O.
//   w1[i][o][k]   = minmax5x5( K[i][o] )
//   wsum[o][g][k] = sum_n w1[64n+g][o][k]
//   score[b,o]    = (sum-1024*min)/(max-min) over conv_same(A[b,:],wsum[o,:])*S[o]
//   n*[b,f]       = argmax_n score[b,64n+f]
//   out[b,f]      = (1/64) sum_g conv_same(A[b,g], w1[ig_g][ig_f]), ig_x = 64n*_x + x
// Implicit GEMMs on mfma_f32_16x16x32_bf16, fp32 hi/lo split (hh+hl+lh).
// k_global = dydx*64 + g -> chunk ks = dydx*2+(g>=32); in-chunk k = quad*8+j.
// R14 = R12 (twice-confirmed best, 141.4/142.0) + kout restructured to the
// R13-phase-4 form as a STANDALONE kernel: grid (16 yb2, 16 b) x 512 thr,
// 8 waves = 4 ftile x 2 xh sharing ONE 36-wide slab -> per-(yb2,b) weight L2
// stream halves (800->400 KB), A staged once, half the blocks. (R13 proved
// this body's correctness but buried it in a cooperative kernel whose
// grid.sync device barriers cost ~90us — fusion refuted, structure kept.)
// kscore frozen (levers R1/R2/R5/R7/R10 all counter-refuted; 3.94M
// SQ_LDS_BANK_CONFLICT is benign 2-way aliasing per R10).

#define NFM 64
#define NMX 4
#define NFC 256
#define HW 1024
#define KK 25

typedef unsigned short u16;
typedef short short8 __attribute__((ext_vector_type(8)));
typedef float f32x4 __attribute__((ext_vector_type(4)));

__device__ __forceinline__ u16 f2bfbits(float f) {
    unsigned int u = __float_as_uint(f);
    u += 0x7fffu + ((u >> 16) & 1u);   // RNE
    return (u16)(u >> 16);
}
__device__ __forceinline__ float bf2f(u16 v) {
    return __uint_as_float(((unsigned int)v) << 16);
}

// --- kw: fused kprep+kpackW. grid (4 gq, 16 ot), 256 thr --------------------
__global__ __launch_bounds__(256) void kw(const float* __restrict__ K,
                                          char* __restrict__ Wpk) {
    __shared__ float wlds[16 * 16 * KK];   // 25600 B
    int gq = blockIdx.x, ot = blockIdx.y, t = threadIdx.x;
    int tg = t >> 4, to = t & 15;
    int g = gq * 16 + tg, o = ot * 16 + to;

    float wacc[KK];
#pragma unroll
    for (int k = 0; k < KK; ++k) wacc[k] = 0.f;
#pragma unroll
    for (int n = 0; n < NMX; ++n) {
        const float* src = K + ((n * NFM + g) * NFC + o) * KK;
        float v[KK];
        float mn = 1e30f, mx = -1e30f;
#pragma unroll
        for (int k = 0; k < KK; ++k) {
            v[k] = src[k];
            mn = fminf(mn, v[k]);
            mx = fmaxf(mx, v[k]);
        }
        float d = mx - mn;
        float r = d > 0.f ? 1.f / d : 0.f;
#pragma unroll
        for (int k = 0; k < KK; ++k) wacc[k] += (v[k] - mn) * r;
    }
#pragma unroll
    for (int k = 0; k < KK; ++k) wlds[(tg * 16 + to) * KK + k] = wacc[k];
    __syncthreads();

    int gh = gq >> 1;
    for (int idx = t; idx < KK * 32; idx += 256) {
        int dydx = idx >> 5, l32 = idx & 31;
        int quad = (gq & 1) * 2 + (l32 >> 4);
        int oo = l32 & 15;
        int l = quad * 16 + oo;
        short8 hs, ls;
#pragma unroll
        for (int j = 0; j < 8; ++j) {
            int gl = (l32 >> 4) * 8 + j;           // g_local in [0,16)
            float v = wlds[(gl * 16 + oo) * KK + dydx];
            u16 h = f2bfbits(v);
            hs[j] = (short)h;
            ls[j] = (short)f2bfbits(v - bf2f(h));
        }
        char* cb = Wpk + (ot * 50 + dydx * 2 + gh) * 2048 + l * 16;
        *(short8*)cb = hs;
        *(short8*)(cb + 1024) = ls;
    }
}

// --- kscore: grid (16 y2, 16 b), 512 thr, 1 block/CU (R3/R6-exact) ----------
#define MFMA6(P, BH, BL)                                                             \
    acc[0][P] = __builtin_amdgcn_mfma_f32_16x16x32_bf16(cah0, BH, acc[0][P], 0, 0, 0); \
    acc[1][P] = __builtin_amdgcn_mfma_f32_16x16x32_bf16(cah1, BH, acc[1][P], 0, 0, 0); \
    acc[0][P] = __builtin_amdgcn_mfma_f32_16x16x32_bf16(cah0, BL, acc[0][P], 0, 0, 0); \
    acc[1][P] = __builtin_amdgcn_mfma_f32_16x16x32_bf16(cah1, BL, acc[1][P], 0, 0, 0); \
    acc[0][P] = __builtin_amdgcn_mfma_f32_16x16x32_bf16(cal0, BH, acc[0][P], 0, 0, 0); \
    acc[1][P] = __builtin_amdgcn_mfma_f32_16x16x32_bf16(cal1, BH, acc[1][P], 0, 0, 0);

__global__ __launch_bounds__(512, 2) void kscore(const float* __restrict__ A,
                                                 const char* __restrict__ Wpk,
                                                 float4* __restrict__ part) {
    __shared__ u16 slabh[6 * 36 * 72];   // 31104 B
    __shared__ u16 slabl[6 * 36 * 72];
    int t = threadIdx.x;
    int y2 = blockIdx.x, b = blockIdx.y;
    int y0 = y2 * 2;
    int lane = t & 63;
    int wv = __builtin_amdgcn_readfirstlane(t >> 6);   // 0..7 = M-tile pair
    int n15 = lane & 15, quad = lane >> 4;

    const float* Ab = A + b * NFM * HW;
    for (int ry = 0; ry < 6; ++ry) {
        int gy = y0 - 2 + ry;
        bool rowok = (gy >= 0) && (gy < 32);
        for (int c = 0; c < 5; ++c) {
            int id2 = c * 512 + t;               // g*36 + xi, < 2304
            if (id2 < 2304) {
                int g = (id2 * 3641) >> 17;      // exact /36 for id2<2304
                int xi = id2 - g * 36;
                float v = 0.f;
                if (rowok && xi >= 2 && xi < 34)
                    v = Ab[g * HW + gy * 32 + xi - 2];
                u16 h = f2bfbits(v);
                u16 l = f2bfbits(v - bf2f(h));
                int idx = (ry * 36 + xi) * 72 + g;
                slabh[idx] = h;
                slabl[idx] = l;
            }
        }
    }
    __syncthreads();

    f32x4 acc[2][4];
#pragma unroll
    for (int m = 0; m < 2; ++m)
#pragma unroll
        for (int p = 0; p < 4; ++p)
#pragma unroll
            for (int r = 0; r < 4; ++r) acc[m][p][r] = 0.f;

    const char* wbase0 = Wpk + (wv * 2) * 50 * 2048 + lane * 16;
    const char* wbase1 = wbase0 + 50 * 2048;
    short8 cah0 = *(const short8*)(wbase0);
    short8 cal0 = *(const short8*)(wbase0 + 1024);
    short8 cah1 = *(const short8*)(wbase1);
    short8 cal1 = *(const short8*)(wbase1 + 1024);

    // B-frag prologue for ks=0: dydx=0, gh=0, dy=dx=0
    int rb0 = n15 * 72 + quad * 8;
    const u16* sh0 = slabh + rb0;
    const u16* sl0 = slabl + rb0;
    short8 bh0 = *(const short8*)(sh0);
    short8 bl0 = *(const short8*)(sl0);
    short8 bh1 = *(const short8*)(sh0 + 16 * 72);
    short8 bl1 = *(const short8*)(sl0 + 16 * 72);
    short8 bh2 = *(const short8*)(sh0 + 36 * 72);
    short8 bl2 = *(const short8*)(sl0 + 36 * 72);
    short8 bh3 = *(const short8*)(sh0 + 52 * 72);
    short8 bl3 = *(const short8*)(sl0 + 52 * 72);

    for (int ks = 0; ks < 50; ++ks) {
        int ksn = ks < 49 ? ks + 1 : 49;
        // next weights (global, 1 ks ahead)
        const char* nb0 = wbase0 + (ksn << 11);
        const char* nb1 = wbase1 + (ksn << 11);
        short8 nah0 = *(const short8*)nb0;
        short8 nal0 = *(const short8*)(nb0 + 1024);
        short8 nah1 = *(const short8*)nb1;
        short8 nal1 = *(const short8*)(nb1 + 1024);
        // next B-fragments (LDS, 1 ks ahead)
        int dydxn = ksn >> 1;
        int ghn = (ksn & 1) * 32;
        int dyn = dydxn / 5, dxn = dydxn - dyn * 5;
        int rbn = (dyn * 36 + n15 + dxn) * 72 + ghn + quad * 8;
        const u16* shn = slabh + rbn;
        const u16* sln = slabl + rbn;
        short8 nh0 = *(const short8*)(shn);
        short8 nl0 = *(const short8*)(sln);
        short8 nh1 = *(const short8*)(shn + 16 * 72);
        short8 nl1 = *(const short8*)(sln + 16 * 72);
        short8 nh2 = *(const short8*)(shn + 36 * 72);
        short8 nl2 = *(const short8*)(sln + 36 * 72);
        short8 nh3 = *(const short8*)(shn + 52 * 72);
        short8 nl3 = *(const short8*)(sln + 52 * 72);
        __builtin_amdgcn_sched_barrier(0);   // pin load-issue before MFMA block

        MFMA6(0, bh0, bl0)
        MFMA6(1, bh1, bl1)
        MFMA6(2, bh2, bl2)
        MFMA6(3, bh3, bl3)

        bh0 = nh0; bl0 = nl0; bh1 = nh1; bl1 = nl1;
        bh2 = nh2; bl2 = nl2; bh3 = nh3; bl3 = nl3;
        cah0 = nah0; cal0 = nal0; cah1 = nah1; cal1 = nal1;
    }

#pragma unroll
    for (int m = 0; m < 2; ++m) {
#pragma unroll
        for (int reg = 0; reg < 4; ++reg) {
            float v0 = acc[m][0][reg], v1 = acc[m][1][reg];
            float v2 = acc[m][2][reg], v3 = acc[m][3][reg];
            float mn = fminf(fminf(v0, v1), fminf(v2, v3));
            float mx = fmaxf(fmaxf(v0, v1), fmaxf(v2, v3));
            float sm = (v0 + v1) + (v2 + v3);
#pragma unroll
            for (int msk = 1; msk <= 8; msk <<= 1) {
                mn = fminf(mn, __shfl_xor(mn, msk, 64));
                mx = fmaxf(mx, __shfl_xor(mx, msk, 64));
                sm += __shfl_xor(sm, msk, 64);
            }
            if (n15 == 0) {
                int o = (wv * 2 + m) * 16 + quad * 4 + reg;
                part[(b * NFC + o) * 16 + y2] = make_float4(mn, mx, sm, 0.f);
            }
        }
    }
}

// --- kpackO: fused score-finalize + argmax + per-batch weight pack ----------
// grid (4 ft, 16 b, 2 half), 256 thr.
__global__ __launch_bounds__(256) void kpackO(const float* __restrict__ K,
                                              const float4* __restrict__ part,
                                              const float* __restrict__ S,
                                              char* __restrict__ Wob) {
    __shared__ float scl[NFC];
    __shared__ int igL[NFM];
    __shared__ __align__(16) char cbuf[25 * 2048];   // 51200 B
    int ft = blockIdx.x, b = blockIdx.y, half = blockIdx.z;
    int t = threadIdx.x;
    {
        const float4* pp = part + (b * NFC + t) * 16;
        float mn = 1e30f, mx = -1e30f, sm = 0.f;
#pragma unroll
        for (int r = 0; r < 16; ++r) {
            float4 p = pp[r];
            mn = fminf(mn, p.x);
            mx = fmaxf(mx, p.y);
            sm += p.z;
        }
        float s = S[t] * (1.f / 64.f);
        float mnv = (s >= 0.f ? mn : mx) * s;
        float mxv = (s >= 0.f ? mx : mn) * s;
        float smv = sm * s;
        float d = mxv - mnv;
        scl[t] = d > 0.f ? (smv - 1024.f * mnv) / d : 0.f;
    }
    __syncthreads();
    if (t < NFM) {
        float best = scl[t];
        int bi = 0;
#pragma unroll
        for (int n = 1; n < NMX; ++n) {
            float v = scl[n * NFM + t];
            if (v > best) { best = v; bi = n; }   // first-max ties
        }
        igL[t] = bi * NFM + t;
    }
    __syncthreads();

    int g32 = t & 31, fh = t >> 5;
    int quad = g32 >> 3, j = g32 & 7;
    char* wdst = Wob + b * 409600 + ft * 102400;

    int i = igL[half * 32 + g32];
#pragma unroll
    for (int e = 0; e < 2; ++e) {
        int f15 = fh * 2 + e;
        int o = igL[ft * 16 + f15];
        const float* src = K + (i * NFC + o) * KK;
        float v[KK];
        float mn = 1e30f, mx = -1e30f;
#pragma unroll
        for (int k = 0; k < KK; ++k) {
            v[k] = src[k];
            mn = fminf(mn, v[k]);
            mx = fmaxf(mx, v[k]);
        }
        float d = mx - mn;
        float r = d > 0.f ? 1.f / d : 0.f;
        char* base = cbuf + (quad * 16 + f15) * 16 + j * 2;
#pragma unroll
        for (int k = 0; k < KK; ++k) {
            float nv = (v[k] - mn) * r;
            u16 h = f2bfbits(nv);
            u16 l = f2bfbits(nv - bf2f(h));
            *(u16*)(base + k * 2048) = h;
            *(u16*)(base + k * 2048 + 1024) = l;
        }
    }
    __syncthreads();
    for (int idx = t; idx < 3200; idx += 256) {   // 25 chunks x 128 f4
        int ch = idx >> 7, w = idx & 127;
        *(float4*)(wdst + (ch * 2 + half) * 2048 + w * 16) =
            *(const float4*)(cbuf + ch * 2048 + w * 16);
    }
}

// --- kout: grid (16 yb2, 16 b), 512 thr, 8 waves = 4 ftile x 2 xh -----------
// One shared 36-wide slab per (yb2,b): A staged once, weight stream 400 KB
// per block (halved). Per-wave work identical to old kout (proven in R13).
__global__ __launch_bounds__(512, 2) void kout(const float* __restrict__ A,
                                               const char* __restrict__ Wob,
                                               float* __restrict__ out) {
    __shared__ u16 slabh[6 * 36 * 72];   // 31104 B
    __shared__ u16 slabl[6 * 36 * 72];
    int t = threadIdx.x;
    int yb2 = blockIdx.x, b = blockIdx.y;
    int y0 = yb2 * 2;
    int lane = t & 63;
    int wv = __builtin_amdgcn_readfirstlane(t >> 6);   // 0..7
    int n15 = lane & 15, quad = lane >> 4;
    int ftile = wv & 3, xh = wv >> 2;
    int xoff = xh * 16;

    const float* Ab = A + b * NFM * HW;
    for (int ry = 0; ry < 6; ++ry) {
        int gy = y0 - 2 + ry;
        bool rowok = (gy >= 0) && (gy < 32);
        for (int c = 0; c < 5; ++c) {
            int id2 = c * 512 + t;               // g*36 + xi, < 2304
            if (id2 < 2304) {
                int g = (id2 * 3641) >> 17;      // exact /36 for id2<2304
                int xi = id2 - g * 36;
                float v = 0.f;
                if (rowok && xi >= 2 && xi < 34)
                    v = Ab[g * HW + gy * 32 + xi - 2];
                u16 h = f2bfbits(v);
                u16 l = f2bfbits(v - bf2f(h));
                int idx = (ry * 36 + xi) * 72 + g;
                slabh[idx] = h;
                slabl[idx] = l;
            }
        }
    }
    __syncthreads();

    f32x4 acc[2];
#pragma unroll
    for (int r = 0; r < 2; ++r)
#pragma unroll
        for (int jr = 0; jr < 4; ++jr) acc[r][jr] = 0.f;

    const char* wbase = Wob + b * 409600 + (ftile * 50) * 2048 + lane * 16;
    short8 cah = *(const short8*)(wbase);
    short8 cal = *(const short8*)(wbase + 1024);

    // B-frag prologue for ks=0
    int rb0 = (xoff + n15) * 72 + quad * 8;
    short8 bh0 = *(const short8*)(slabh + rb0);
    short8 bl0 = *(const short8*)(slabl + rb0);
    short8 bh1 = *(const short8*)(slabh + rb0 + 36 * 72);
    short8 bl1 = *(const short8*)(slabl + rb0 + 36 * 72);

    for (int ks = 0; ks < 50; ++ks) {
        int ksn = ks < 49 ? ks + 1 : 49;
        const char* nb = wbase + (ksn << 11);
        short8 nah = *(const short8*)nb;
        short8 nal = *(const short8*)(nb + 1024);

        int dydxn = ksn >> 1;
        int ghn = (ksn & 1) * 32;
        int dyn = dydxn / 5, dxn = dydxn - dyn * 5;
        int rbn = (dyn * 36 + xoff + n15 + dxn) * 72 + ghn + quad * 8;
        short8 nh0 = *(const short8*)(slabh + rbn);
        short8 nl0 = *(const short8*)(slabl + rbn);
        short8 nh1 = *(const short8*)(slabh + rbn + 36 * 72);
        short8 nl1 = *(const short8*)(slabl + rbn + 36 * 72);
        __builtin_amdgcn_sched_barrier(0);

        acc[0] = __builtin_amdgcn_mfma_f32_16x16x32_bf16(cah, bh0, acc[0], 0, 0, 0);
        acc[1] = __builtin_amdgcn_mfma_f32_16x16x32_bf16(cah, bh1, acc[1], 0, 0, 0);
        acc[0] = __builtin_amdgcn_mfma_f32_16x16x32_bf16(cah, bl0, acc[0], 0, 0, 0);
        acc[1] = __builtin_amdgcn_mfma_f32_16x16x32_bf16(cah, bl1, acc[1], 0, 0, 0);
        acc[0] = __builtin_amdgcn_mfma_f32_16x16x32_bf16(cal, bh0, acc[0], 0, 0, 0);
        acc[1] = __builtin_amdgcn_mfma_f32_16x16x32_bf16(cal, bh1, acc[1], 0, 0, 0);

        bh0 = nh0; bl0 = nl0; bh1 = nh1; bl1 = nl1;
        cah = nah;
        cal = nal;
    }

#pragma unroll
    for (int r = 0; r < 2; ++r)
#pragma unroll
        for (int reg = 0; reg < 4; ++reg) {
            int f = ftile * 16 + quad * 4 + reg;
            out[(b * NFM + f) * HW + (y0 + r) * 32 + xoff + n15] =
                acc[r][reg] * (1.f / 64.f);
        }
}

extern "C" void kernel_launch(void* const* d_in, const int* in_sizes, int n_in,
                              void* d_out, int out_size, void* d_ws, size_t ws_size,
                              hipStream_t stream) {
    const float* A = (const float*)d_in[0];   // (16,64,32,32) f32
    const float* K = (const float*)d_in[1];   // (256,256,5,5) f32
    const float* S = (const float*)d_in[2];   // (256,) f32
    float* out = (float*)d_out;               // (16,64,32,32) f32

    char* ws = (char*)d_ws;
    char*   Wob   = ws;                         // [0, 6,553,600) written by kpackO
    char*   Wpk   = ws;                         // [0, 1,638,400) dead before kpackO
    float4* part  = (float4*)(ws + 6553600);    // [6.55M, 7.60M) 16*256*16 f4

    kw<<<dim3(4, 16), dim3(256), 0, stream>>>(K, Wpk);
    kscore<<<dim3(16, 16), dim3(512), 0, stream>>>(A, Wpk, part);
    kpackO<<<dim3(4, 16, 2), dim3(256), 0, stream>>>(K, part, S, Wob);
    kout<<<dim3(16, 16), dim3(512), 0, stream>>>(A, Wob, out);
}